// Round 1
// baseline (2544.818 us; speedup 1.0000x reference)
//
#include <hip/hip_runtime.h>
#include <stdint.h>

// Problem constants (B,N,DIM,HEADS,DEPTH = 2,2048,1024,16,6)
#define B_     2
#define N_TOK  2048
#define DIM_   1024
#define HEADS_ 16
#define DEPTH_ 6
#define HID_   4096
#define DH_    64
#define MROWS_ (B_ * N_TOK)       // 4096 token rows
#define SCALE_ 0.125f             // DH^-0.5

typedef __bf16 bf16x8 __attribute__((ext_vector_type(8)));
typedef float  f32x4  __attribute__((ext_vector_type(4)));

__device__ __forceinline__ unsigned short f2bf(float f) {
  // round-to-nearest-even fp32 -> bf16 (no NaN handling; inputs are sane)
  unsigned int u = __float_as_uint(f);
  u += 0x7FFFu + ((u >> 16) & 1u);
  return (unsigned short)(u >> 16);
}

__device__ __forceinline__ f32x4 mfma16(bf16x8 a, bf16x8 b, f32x4 c) {
  return __builtin_amdgcn_mfma_f32_16x16x32_bf16(a, b, c, 0, 0, 0);
}

// async global->LDS, 16B per lane. dst must be wave-uniform; HW adds lane*16.
__device__ __forceinline__ void gload_lds16(const unsigned short* g, unsigned short* l) {
  __builtin_amdgcn_global_load_lds(
      (const __attribute__((address_space(1))) unsigned int*)g,
      (__attribute__((address_space(3))) unsigned int*)l, 16, 0, 0);
}

// ---------------------------------------------------------------------------
// LayerNorm: one block per token row; fp32 in (x), bf16 out (h). g/b fp32.
// ---------------------------------------------------------------------------
__global__ __launch_bounds__(256) void ln_kernel(
    const float* __restrict__ x, unsigned short* __restrict__ h,
    const float* __restrict__ gw, const float* __restrict__ bw) {
  int row = blockIdx.x;
  int t = threadIdx.x;
  const float* xr = x + (size_t)row * DIM_;
  float4 v = reinterpret_cast<const float4*>(xr)[t];
  float s = v.x + v.y + v.z + v.w;
  float q = v.x * v.x + v.y * v.y + v.z * v.z + v.w * v.w;
  for (int m = 1; m < 64; m <<= 1) { s += __shfl_xor(s, m); q += __shfl_xor(q, m); }
  __shared__ float rs[4], rq[4];
  int lane = t & 63, w = t >> 6;
  if (lane == 0) { rs[w] = s; rq[w] = q; }
  __syncthreads();
  s = rs[0] + rs[1] + rs[2] + rs[3];
  q = rq[0] + rq[1] + rq[2] + rq[3];
  float mean = s * (1.0f / DIM_);
  float var  = q * (1.0f / DIM_) - mean * mean;
  float rstd = rsqrtf(var + 1e-5f);
  float4 gv = reinterpret_cast<const float4*>(gw)[t];
  float4 bv = reinterpret_cast<const float4*>(bw)[t];
  ushort4 ov;
  ov.x = f2bf((v.x - mean) * rstd * gv.x + bv.x);
  ov.y = f2bf((v.y - mean) * rstd * gv.y + bv.y);
  ov.z = f2bf((v.z - mean) * rstd * gv.z + bv.z);
  ov.w = f2bf((v.w - mean) * rstd * gv.w + bv.w);
  reinterpret_cast<ushort4*>(h + (size_t)row * DIM_)[t] = ov;
}

// ---------------------------------------------------------------------------
// Weight transpose+convert: W fp32 [K][Nn] -> Wt bf16 [Nn][K].
// grid (Nn/32, K/32), 256 threads (32x8).
// ---------------------------------------------------------------------------
__global__ __launch_bounds__(256) void transpose_w(
    const float* __restrict__ W, unsigned short* __restrict__ Wt, int K, int Nn) {
  __shared__ unsigned short tile[32][33];
  int n0 = blockIdx.x * 32, k0 = blockIdx.y * 32;
  int tx = threadIdx.x & 31, ty = threadIdx.x >> 5;
  #pragma unroll
  for (int r = ty; r < 32; r += 8)
    tile[r][tx] = f2bf(W[(size_t)(k0 + r) * Nn + n0 + tx]);
  __syncthreads();
  #pragma unroll
  for (int r = ty; r < 32; r += 8)
    Wt[(size_t)(n0 + r) * K + k0 + tx] = tile[tx][r];
}

// ---------------------------------------------------------------------------
// V transpose: qkv bf16 [4096][3072] (v at cols 2048..3071) -> vt [32][64][2048]
// grid (N_TOK/64, B_*HEADS_), 256 threads.
// ---------------------------------------------------------------------------
__global__ __launch_bounds__(256) void vtrans(
    const unsigned short* __restrict__ qkv, unsigned short* __restrict__ vt) {
  __shared__ unsigned short t[64][65];
  int b = blockIdx.y >> 4, h = blockIdx.y & 15;
  int n0 = blockIdx.x * 64;
  int tx = threadIdx.x & 63, ty = threadIdx.x >> 6;
  const unsigned short* src = qkv + ((size_t)(b * N_TOK + n0)) * (3 * DIM_) + 2 * DIM_ + h * DH_;
  #pragma unroll
  for (int r = ty; r < 64; r += 4) t[r][tx] = src[(size_t)r * (3 * DIM_) + tx];
  __syncthreads();
  unsigned short* dst = vt + ((size_t)blockIdx.y * DH_) * N_TOK + n0;
  #pragma unroll
  for (int r = ty; r < 64; r += 4) dst[(size_t)r * N_TOK + tx] = t[tx][r];
}

// ---------------------------------------------------------------------------
// bf16 MFMA GEMM, m97-structure: 128x128 tile, BK=32, 4 waves (2x2) x 64x64,
// double-buffered LDS via global_load_lds(16B), 1 barrier / K-step.
// A bf16 [M][K] row-major, Bt bf16 [Nn][K] (i.e. B^T), bias fp32 [Nn].
// EP 0: out bf16 = acc+bias ; EP 1: out bf16 = gelu(acc+bias) ;
// EP 2: out fp32 (in-place) Cf += acc+bias  (residual).
// ---------------------------------------------------------------------------
#define EP_BF16       0
#define EP_BF16_GELU  1
#define EP_F32_RESID  2

template <int EP>
__global__ __launch_bounds__(256) void gemm_kernel(
    const unsigned short* __restrict__ A, const unsigned short* __restrict__ Bt,
    const float* __restrict__ bias, unsigned short* __restrict__ Cb,
    float* __restrict__ Cf, int M, int Nn, int K) {
  int brow = blockIdx.x * 128;
  int bcol = blockIdx.y * 128;
  int lane = threadIdx.x & 63, wave = threadIdx.x >> 6;
  int i = lane & 15, g = lane >> 4;
  int wr = wave >> 1, wc = wave & 1;
  __shared__ unsigned short Al[2][128 * 32];
  __shared__ unsigned short Bl[2][128 * 32];

  f32x4 zero4 = {0.f, 0.f, 0.f, 0.f};
  f32x4 acc[4][4];
  #pragma unroll
  for (int m = 0; m < 4; ++m)
    #pragma unroll
    for (int n = 0; n < 4; ++n) acc[m][n] = zero4;

  // stage one 128x32 bf16 tile for A and B: 8 chunks of 1KB each, 2 per wave.
  auto stage = [&](int buf, int k0) {
    #pragma unroll
    for (int c = 0; c < 2; ++c) {
      int ch = wave * 2 + c;                 // wave-uniform chunk id
      int row = ch * 16 + (lane >> 2);
      int k8 = (lane & 3) * 8;
      gload_lds16(A + (size_t)(brow + row) * K + k0 + k8, &Al[buf][ch * 512]);
      gload_lds16(Bt + (size_t)(bcol + row) * K + k0 + k8, &Bl[buf][ch * 512]);
    }
  };

  int NT = K / 32;
  stage(0, 0);
  for (int t = 0; t < NT; ++t) {
    __syncthreads();                          // stage(t) drained (vmcnt0+barrier)
    if (t + 1 < NT) stage((t + 1) & 1, (t + 1) * 32);
    int buf = t & 1;
    bf16x8 af[4], bfr[4];
    #pragma unroll
    for (int m = 0; m < 4; ++m)
      af[m] = *reinterpret_cast<const bf16x8*>(&Al[buf][(wr * 64 + m * 16 + i) * 32 + g * 8]);
    #pragma unroll
    for (int n = 0; n < 4; ++n)
      bfr[n] = *reinterpret_cast<const bf16x8*>(&Bl[buf][(wc * 64 + n * 16 + i) * 32 + g * 8]);
    #pragma unroll
    for (int m = 0; m < 4; ++m)
      #pragma unroll
      for (int n = 0; n < 4; ++n)
        acc[m][n] = mfma16(af[m], bfr[n], acc[m][n]);
  }

  int rowbase = brow + wr * 64;
  int colbase = bcol + wc * 64;
  #pragma unroll
  for (int m = 0; m < 4; ++m) {
    #pragma unroll
    for (int n = 0; n < 4; ++n) {
      int col = colbase + n * 16 + i;
      float bs = bias[col];
      #pragma unroll
      for (int r = 0; r < 4; ++r) {
        int row = rowbase + m * 16 + g * 4 + r;
        float v = acc[m][n][r] + bs;
        if constexpr (EP == EP_BF16) {
          Cb[(size_t)row * Nn + col] = f2bf(v);
        } else if constexpr (EP == EP_BF16_GELU) {
          float gg = 0.5f * v * (1.0f + erff(v * 0.70710678118f));
          Cb[(size_t)row * Nn + col] = f2bf(gg);
        } else {
          size_t idx = (size_t)row * Nn + col;
          Cf[idx] = Cf[idx] + v;              // residual, in-place
        }
      }
    }
  }
}

// ---------------------------------------------------------------------------
// Flash attention fwd, bf16 MFMA, fp32 online softmax.
// grid (N_TOK/128, B_*HEADS_), 256 threads = 4 waves x 32 q-rows.
// qkv bf16 [4096][3072]; vt bf16 [32][64][2048]; o bf16 [4096][1024].
// ---------------------------------------------------------------------------
__global__ __launch_bounds__(256, 2) void attn_kernel(
    const unsigned short* __restrict__ qkv, const unsigned short* __restrict__ vt,
    unsigned short* __restrict__ o) {
  int qt = blockIdx.x, bh = blockIdx.y;
  int b = bh >> 4, h = bh & 15;
  int tid = threadIdx.x, lane = tid & 63, wave = tid >> 6;
  int i = lane & 15, g = lane >> 4;
  __shared__ unsigned short Kl[2][64][72];   // [j][d], pad to 72 for banks
  __shared__ unsigned short Vl[2][64][72];   // [d][j]
  __shared__ unsigned short Pl[4][2][16][72];// per-wave P relayout buffer

  const size_t qstr = 3 * DIM_;
  int qrow0 = qt * 128 + wave * 32;

  bf16x8 qa[2][2];
  #pragma unroll
  for (int sub = 0; sub < 2; ++sub)
    #pragma unroll
    for (int ks = 0; ks < 2; ++ks)
      qa[sub][ks] = *reinterpret_cast<const bf16x8*>(
          qkv + (size_t)(b * N_TOK + qrow0 + sub * 16 + i) * qstr + h * DH_ + ks * 32 + g * 8);

  f32x4 zero4 = {0.f, 0.f, 0.f, 0.f};
  f32x4 oacc[2][4];
  float mrow[2][4], lrow[2][4];
  #pragma unroll
  for (int sub = 0; sub < 2; ++sub) {
    #pragma unroll
    for (int dt = 0; dt < 4; ++dt) oacc[sub][dt] = zero4;
    #pragma unroll
    for (int r = 0; r < 4; ++r) { mrow[sub][r] = -1e30f; lrow[sub][r] = 0.f; }
  }

  const unsigned short* kbase = qkv + (size_t)b * N_TOK * qstr + DIM_ + h * DH_;
  const unsigned short* vbase = vt + (size_t)bh * DH_ * N_TOK;
  uint4 kreg[2], vreg[2];

  auto issue = [&](int j0) {
    #pragma unroll
    for (int p = 0; p < 2; ++p) {
      int flat = p * 256 + tid;
      int row = flat >> 3, c8 = (flat & 7) * 8;
      kreg[p] = *reinterpret_cast<const uint4*>(kbase + (size_t)(j0 + row) * qstr + c8);
      vreg[p] = *reinterpret_cast<const uint4*>(vbase + (size_t)row * N_TOK + j0 + c8);
    }
  };
  auto commit = [&](int buf) {
    #pragma unroll
    for (int p = 0; p < 2; ++p) {
      int flat = p * 256 + tid;
      int row = flat >> 3, c8 = (flat & 7) * 8;
      *reinterpret_cast<uint4*>(&Kl[buf][row][c8]) = kreg[p];
      *reinterpret_cast<uint4*>(&Vl[buf][row][c8]) = vreg[p];
    }
  };

  issue(0); commit(0);
  int cur = 0;
  for (int jt = 0; jt < N_TOK / 64; ++jt) {
    __syncthreads();                          // K/V tile visible block-wide
    if (jt + 1 < N_TOK / 64) issue((jt + 1) * 64);   // hide HBM under compute (T14)

    bf16x8 kb[4][2], vb[4][2];
    #pragma unroll
    for (int nt = 0; nt < 4; ++nt)
      #pragma unroll
      for (int ks = 0; ks < 2; ++ks)
        kb[nt][ks] = *reinterpret_cast<const bf16x8*>(&Kl[cur][nt * 16 + i][ks * 32 + g * 8]);
    #pragma unroll
    for (int dt = 0; dt < 4; ++dt)
      #pragma unroll
      for (int js = 0; js < 2; ++js)
        vb[dt][js] = *reinterpret_cast<const bf16x8*>(&Vl[cur][dt * 16 + i][js * 32 + g * 8]);

    #pragma unroll
    for (int sub = 0; sub < 2; ++sub) {
      f32x4 s[4];
      #pragma unroll
      for (int nt = 0; nt < 4; ++nt) {
        s[nt] = zero4;
        #pragma unroll
        for (int ks = 0; ks < 2; ++ks) s[nt] = mfma16(qa[sub][ks], kb[nt][ks], s[nt]);
        s[nt] = s[nt] * SCALE_;
      }
      float tmax[4];
      #pragma unroll
      for (int r = 0; r < 4; ++r)
        tmax[r] = fmaxf(fmaxf(s[0][r], s[1][r]), fmaxf(s[2][r], s[3][r]));
      for (int m = 1; m < 16; m <<= 1) {
        #pragma unroll
        for (int r = 0; r < 4; ++r) tmax[r] = fmaxf(tmax[r], __shfl_xor(tmax[r], m));
      }
      float al[4], ps[4];
      #pragma unroll
      for (int r = 0; r < 4; ++r) {
        float mn = fmaxf(mrow[sub][r], tmax[r]);
        al[r] = __expf(mrow[sub][r] - mn);
        mrow[sub][r] = mn;
        ps[r] = 0.f;
      }
      #pragma unroll
      for (int nt = 0; nt < 4; ++nt)
        #pragma unroll
        for (int r = 0; r < 4; ++r) {
          float p = __expf(s[nt][r] - mrow[sub][r]);
          ps[r] += p;
          Pl[wave][sub][g * 4 + r][nt * 16 + i] = f2bf(p);
        }
      for (int m = 1; m < 16; m <<= 1) {
        #pragma unroll
        for (int r = 0; r < 4; ++r) ps[r] += __shfl_xor(ps[r], m);
      }
      #pragma unroll
      for (int r = 0; r < 4; ++r) lrow[sub][r] = lrow[sub][r] * al[r] + ps[r];
      #pragma unroll
      for (int dt = 0; dt < 4; ++dt)
        #pragma unroll
        for (int r = 0; r < 4; ++r) oacc[sub][dt][r] *= al[r];
      bf16x8 pa[2];
      #pragma unroll
      for (int js = 0; js < 2; ++js)
        pa[js] = *reinterpret_cast<const bf16x8*>(&Pl[wave][sub][i][js * 32 + g * 8]);
      #pragma unroll
      for (int dt = 0; dt < 4; ++dt)
        #pragma unroll
        for (int js = 0; js < 2; ++js)
          oacc[sub][dt] = mfma16(pa[js], vb[dt][js], oacc[sub][dt]);
    }
    if (jt + 1 < N_TOK / 64) commit(cur ^ 1); // write next tile into other buffer
    cur ^= 1;
  }

  unsigned short* ob = o + (size_t)(b * N_TOK + qrow0) * DIM_ + h * DH_;
  #pragma unroll
  for (int sub = 0; sub < 2; ++sub)
    #pragma unroll
    for (int r = 0; r < 4; ++r) {
      float inv = 1.0f / lrow[sub][r];
      #pragma unroll
      for (int dt = 0; dt < 4; ++dt)
        ob[(size_t)(sub * 16 + g * 4 + r) * DIM_ + dt * 16 + i] = f2bf(oacc[sub][dt][r] * inv);
    }
}

// ---------------------------------------------------------------------------
extern "C" void kernel_launch(void* const* d_in, const int* in_sizes, int n_in,
                              void* d_out, int out_size, void* d_ws, size_t ws_size,
                              hipStream_t stream) {
  (void)in_sizes; (void)n_in; (void)out_size; (void)ws_size;
  const float* x_in = (const float*)d_in[0];
  const float* Wqkv = (const float*)d_in[1];
  const float* bqkv = (const float*)d_in[2];
  const float* Wo   = (const float*)d_in[3];
  const float* bo   = (const float*)d_in[4];
  const float* W1   = (const float*)d_in[5];
  const float* bm1  = (const float*)d_in[6];
  const float* W2   = (const float*)d_in[7];
  const float* bm2  = (const float*)d_in[8];
  const float* ln1g = (const float*)d_in[9];
  const float* ln1b = (const float*)d_in[10];
  const float* ln2g = (const float*)d_in[11];
  const float* ln2b = (const float*)d_in[12];
  float* x = (float*)d_out;                  // residual stream, fp32, in-place

  char* ws = (char*)d_ws;                    // ~88 MB used
  unsigned short* wt  = (unsigned short*)(ws);                              // 8 MB (max weight)
  unsigned short* hbf = (unsigned short*)(ws + (size_t)8  * 1024 * 1024);   // 8 MB
  unsigned short* qkv = (unsigned short*)(ws + (size_t)16 * 1024 * 1024);   // 24 MB
  unsigned short* vtb = (unsigned short*)(ws + (size_t)40 * 1024 * 1024);   // 8 MB
  unsigned short* ob  = (unsigned short*)(ws + (size_t)48 * 1024 * 1024);   // 8 MB
  unsigned short* mid = (unsigned short*)(ws + (size_t)56 * 1024 * 1024);   // 32 MB

  hipMemcpyAsync(x, x_in, (size_t)MROWS_ * DIM_ * sizeof(float),
                 hipMemcpyDeviceToDevice, stream);

  for (int l = 0; l < DEPTH_; ++l) {
    const float* wqkv_l = Wqkv + (size_t)l * DIM_ * 3 * DIM_;
    const float* wo_l   = Wo   + (size_t)l * DIM_ * DIM_;
    const float* w1_l   = W1   + (size_t)l * DIM_ * HID_;
    const float* w2_l   = W2   + (size_t)l * HID_ * DIM_;

    // --- PreNorm + Attention ---
    ln_kernel<<<MROWS_, 256, 0, stream>>>(x, hbf, ln1g + l * DIM_, ln1b + l * DIM_);
    transpose_w<<<dim3(3 * DIM_ / 32, DIM_ / 32), 256, 0, stream>>>(wqkv_l, wt, DIM_, 3 * DIM_);
    gemm_kernel<EP_BF16><<<dim3(MROWS_ / 128, 3 * DIM_ / 128), 256, 0, stream>>>(
        hbf, wt, bqkv + (size_t)l * 3 * DIM_, qkv, nullptr, MROWS_, 3 * DIM_, DIM_);
    vtrans<<<dim3(N_TOK / 64, B_ * HEADS_), 256, 0, stream>>>(qkv, vtb);
    attn_kernel<<<dim3(N_TOK / 128, B_ * HEADS_), 256, 0, stream>>>(qkv, vtb, ob);
    transpose_w<<<dim3(DIM_ / 32, DIM_ / 32), 256, 0, stream>>>(wo_l, wt, DIM_, DIM_);
    gemm_kernel<EP_F32_RESID><<<dim3(MROWS_ / 128, DIM_ / 128), 256, 0, stream>>>(
        ob, wt, bo + (size_t)l * DIM_, nullptr, x, MROWS_, DIM_, DIM_);

    // --- PreNorm + MLP ---
    ln_kernel<<<MROWS_, 256, 0, stream>>>(x, hbf, ln2g + l * DIM_, ln2b + l * DIM_);
    transpose_w<<<dim3(HID_ / 32, DIM_ / 32), 256, 0, stream>>>(w1_l, wt, DIM_, HID_);
    gemm_kernel<EP_BF16_GELU><<<dim3(MROWS_ / 128, HID_ / 128), 256, 0, stream>>>(
        hbf, wt, bm1 + (size_t)l * HID_, mid, nullptr, MROWS_, HID_, DIM_);
    transpose_w<<<dim3(DIM_ / 32, HID_ / 32), 256, 0, stream>>>(w2_l, wt, HID_, DIM_);
    gemm_kernel<EP_F32_RESID><<<dim3(MROWS_ / 128, DIM_ / 128), 256, 0, stream>>>(
        mid, wt, bm2 + (size_t)l * DIM_, nullptr, x, MROWS_, DIM_, HID_);
  }
}

// Round 2
// 2251.243 us; speedup vs baseline: 1.1304x; 1.1304x over previous
//
#include <hip/hip_runtime.h>
#include <stdint.h>

// Problem constants (B,N,DIM,HEADS,DEPTH = 2,2048,1024,16,6)
#define B_     2
#define N_TOK  2048
#define DIM_   1024
#define HEADS_ 16
#define DEPTH_ 6
#define HID_   4096
#define DH_    64
#define MROWS_ (B_ * N_TOK)       // 4096 token rows
#define SCALE_ 0.125f             // DH^-0.5

typedef __bf16 bf16x8 __attribute__((ext_vector_type(8)));
typedef float  f32x4  __attribute__((ext_vector_type(4)));
typedef float  f32x16 __attribute__((ext_vector_type(16)));

__device__ __forceinline__ unsigned short f2bf(float f) {
  unsigned int u = __float_as_uint(f);
  u += 0x7FFFu + ((u >> 16) & 1u);
  return (unsigned short)(u >> 16);
}

__device__ __forceinline__ f32x4 mfma16(bf16x8 a, bf16x8 b, f32x4 c) {
  return __builtin_amdgcn_mfma_f32_16x16x32_bf16(a, b, c, 0, 0, 0);
}
__device__ __forceinline__ f32x16 mfma32(bf16x8 a, bf16x8 b, f32x16 c) {
  return __builtin_amdgcn_mfma_f32_32x32x16_bf16(a, b, c, 0, 0, 0);
}
__device__ __forceinline__ f32x16 zero16() {
  f32x16 z;
  #pragma unroll
  for (int e = 0; e < 16; ++e) z[e] = 0.f;
  return z;
}

// async global->LDS, 16B per lane. dst must be wave-uniform; HW adds lane*16.
__device__ __forceinline__ void gload_lds16(const unsigned short* g, unsigned short* l) {
  __builtin_amdgcn_global_load_lds(
      (const __attribute__((address_space(1))) unsigned int*)g,
      (__attribute__((address_space(3))) unsigned int*)l, 16, 0, 0);
}

// ---------------------------------------------------------------------------
// LayerNorm: one block per token row; fp32 in (x), bf16 out (h).
// ---------------------------------------------------------------------------
__global__ __launch_bounds__(256) void ln_kernel(
    const float* __restrict__ x, unsigned short* __restrict__ h,
    const float* __restrict__ gw, const float* __restrict__ bw) {
  int row = blockIdx.x;
  int t = threadIdx.x;
  const float* xr = x + (size_t)row * DIM_;
  float4 v = reinterpret_cast<const float4*>(xr)[t];
  float s = v.x + v.y + v.z + v.w;
  float q = v.x * v.x + v.y * v.y + v.z * v.z + v.w * v.w;
  for (int m = 1; m < 64; m <<= 1) { s += __shfl_xor(s, m); q += __shfl_xor(q, m); }
  __shared__ float rs[4], rq[4];
  int lane = t & 63, w = t >> 6;
  if (lane == 0) { rs[w] = s; rq[w] = q; }
  __syncthreads();
  s = rs[0] + rs[1] + rs[2] + rs[3];
  q = rq[0] + rq[1] + rq[2] + rq[3];
  float mean = s * (1.0f / DIM_);
  float var  = q * (1.0f / DIM_) - mean * mean;
  float rstd = rsqrtf(var + 1e-5f);
  float4 gv = reinterpret_cast<const float4*>(gw)[t];
  float4 bv = reinterpret_cast<const float4*>(bw)[t];
  ushort4 ov;
  ov.x = f2bf((v.x - mean) * rstd * gv.x + bv.x);
  ov.y = f2bf((v.y - mean) * rstd * gv.y + bv.y);
  ov.z = f2bf((v.z - mean) * rstd * gv.z + bv.z);
  ov.w = f2bf((v.w - mean) * rstd * gv.w + bv.w);
  reinterpret_cast<ushort4*>(h + (size_t)row * DIM_)[t] = ov;
}

// ---------------------------------------------------------------------------
// Weight transpose+convert: W fp32 [K][Nn] -> Wt bf16 [Nn][K].
// ---------------------------------------------------------------------------
__global__ __launch_bounds__(256) void transpose_w(
    const float* __restrict__ W, unsigned short* __restrict__ Wt, int K, int Nn) {
  __shared__ unsigned short tile[32][33];
  int n0 = blockIdx.x * 32, k0 = blockIdx.y * 32;
  int tx = threadIdx.x & 31, ty = threadIdx.x >> 5;
  #pragma unroll
  for (int r = ty; r < 32; r += 8)
    tile[r][tx] = f2bf(W[(size_t)(k0 + r) * Nn + n0 + tx]);
  __syncthreads();
  #pragma unroll
  for (int r = ty; r < 32; r += 8)
    Wt[(size_t)(n0 + r) * K + k0 + tx] = tile[tx][r];
}

// ---------------------------------------------------------------------------
// V transpose: qkv bf16 [4096][3072] (v cols 2048..3071) -> vt [32][64][2048]
// ---------------------------------------------------------------------------
__global__ __launch_bounds__(256) void vtrans(
    const unsigned short* __restrict__ qkv, unsigned short* __restrict__ vt) {
  __shared__ unsigned short t[64][65];
  int b = blockIdx.y >> 4, h = blockIdx.y & 15;
  int n0 = blockIdx.x * 64;
  int tx = threadIdx.x & 63, ty = threadIdx.x >> 6;
  const unsigned short* src = qkv + ((size_t)(b * N_TOK + n0)) * (3 * DIM_) + 2 * DIM_ + h * DH_;
  #pragma unroll
  for (int r = ty; r < 64; r += 4) t[r][tx] = src[(size_t)r * (3 * DIM_) + tx];
  __syncthreads();
  unsigned short* dst = vt + ((size_t)blockIdx.y * DH_) * N_TOK + n0;
  #pragma unroll
  for (int r = ty; r < 64; r += 4) dst[(size_t)r * N_TOK + tx] = t[tx][r];
}

// ---------------------------------------------------------------------------
// bf16 MFMA GEMM (m97-structure), unchanged from R1.
// ---------------------------------------------------------------------------
#define EP_BF16       0
#define EP_BF16_GELU  1
#define EP_F32_RESID  2

template <int EP>
__global__ __launch_bounds__(256) void gemm_kernel(
    const unsigned short* __restrict__ A, const unsigned short* __restrict__ Bt,
    const float* __restrict__ bias, unsigned short* __restrict__ Cb,
    float* __restrict__ Cf, int M, int Nn, int K) {
  int brow = blockIdx.x * 128;
  int bcol = blockIdx.y * 128;
  int lane = threadIdx.x & 63, wave = threadIdx.x >> 6;
  int i = lane & 15, g = lane >> 4;
  int wr = wave >> 1, wc = wave & 1;
  __shared__ unsigned short Al[2][128 * 32];
  __shared__ unsigned short Bl[2][128 * 32];

  f32x4 zero4 = {0.f, 0.f, 0.f, 0.f};
  f32x4 acc[4][4];
  #pragma unroll
  for (int m = 0; m < 4; ++m)
    #pragma unroll
    for (int n = 0; n < 4; ++n) acc[m][n] = zero4;

  auto stage = [&](int buf, int k0) {
    #pragma unroll
    for (int c = 0; c < 2; ++c) {
      int ch = wave * 2 + c;
      int row = ch * 16 + (lane >> 2);
      int k8 = (lane & 3) * 8;
      gload_lds16(A + (size_t)(brow + row) * K + k0 + k8, &Al[buf][ch * 512]);
      gload_lds16(Bt + (size_t)(bcol + row) * K + k0 + k8, &Bl[buf][ch * 512]);
    }
  };

  int NT = K / 32;
  stage(0, 0);
  for (int t = 0; t < NT; ++t) {
    __syncthreads();
    if (t + 1 < NT) stage((t + 1) & 1, (t + 1) * 32);
    int buf = t & 1;
    bf16x8 af[4], bfr[4];
    #pragma unroll
    for (int m = 0; m < 4; ++m)
      af[m] = *reinterpret_cast<const bf16x8*>(&Al[buf][(wr * 64 + m * 16 + i) * 32 + g * 8]);
    #pragma unroll
    for (int n = 0; n < 4; ++n)
      bfr[n] = *reinterpret_cast<const bf16x8*>(&Bl[buf][(wc * 64 + n * 16 + i) * 32 + g * 8]);
    #pragma unroll
    for (int m = 0; m < 4; ++m)
      #pragma unroll
      for (int n = 0; n < 4; ++n)
        acc[m][n] = mfma16(af[m], bfr[n], acc[m][n]);
  }

  int rowbase = brow + wr * 64;
  int colbase = bcol + wc * 64;
  #pragma unroll
  for (int m = 0; m < 4; ++m) {
    #pragma unroll
    for (int n = 0; n < 4; ++n) {
      int col = colbase + n * 16 + i;
      float bs = bias[col];
      #pragma unroll
      for (int r = 0; r < 4; ++r) {
        int row = rowbase + m * 16 + g * 4 + r;
        float v = acc[m][n][r] + bs;
        if constexpr (EP == EP_BF16) {
          Cb[(size_t)row * Nn + col] = f2bf(v);
        } else if constexpr (EP == EP_BF16_GELU) {
          float gg = 0.5f * v * (1.0f + erff(v * 0.70710678118f));
          Cb[(size_t)row * Nn + col] = f2bf(gg);
        } else {
          size_t idx = (size_t)row * Nn + col;
          Cf[idx] = Cf[idx] + v;
        }
      }
    }
  }
}

// ---------------------------------------------------------------------------
// Flash attention fwd, swapped-QK^T 32x32 MFMA, in-register softmax.
// grid (N_TOK/128, B_*HEADS_), 256 threads = 4 waves x 32 q-rows.
// Each lane owns ONE q-row (q = lane&31); lane pair (lane, lane^32) share it.
//   S^T[kv][q] = mfma32(K_frag, Q_frag)  -> lane: 32 kv vals (2 subtiles x 16)
//   softmax in-register: in-lane reduce + one shfl_xor(32)
//   P^T -> bf16 B-frags via pack + shfl_xor(32) word exchange
//   O^T[d][q] = mfma32(Vt_frag, P_frag)  -> rescale factor lane-local
// K/V^T tiles in LDS with XOR swizzle (col16B ^= row&7), double-buffered.
// ---------------------------------------------------------------------------
__global__ __launch_bounds__(256) void attn_kernel(
    const unsigned short* __restrict__ qkv, const unsigned short* __restrict__ vt,
    unsigned short* __restrict__ o) {
  int qt = blockIdx.x, bh = blockIdx.y;
  int b = bh >> 4, h = bh & 15;
  int tid = threadIdx.x, lane = tid & 63, wave = tid >> 6;
  int q5 = lane & 31, hi = lane >> 5;
  __shared__ unsigned short Kl[2][64 * 64];
  __shared__ unsigned short Vl[2][64 * 64];

  const size_t qstr = 3 * DIM_;
  int qrow = qt * 128 + wave * 32 + q5;

  // Q B-frags: col=q(lane&31), k = d = f*16 + 8*hi + j  (direct from global)
  bf16x8 qa[4];
  #pragma unroll
  for (int f = 0; f < 4; ++f)
    qa[f] = *reinterpret_cast<const bf16x8*>(
        qkv + (size_t)(b * N_TOK + qrow) * qstr + h * DH_ + f * 16 + hi * 8);

  f32x16 oacc[2];
  oacc[0] = zero16(); oacc[1] = zero16();
  float m = -1e30f, l = 0.f;

  const unsigned short* kbase = qkv + (size_t)b * N_TOK * qstr + DIM_ + h * DH_;
  const unsigned short* vbase = vt + (size_t)bh * DH_ * N_TOK;
  uint4 kreg[2], vreg[2];

  auto issue = [&](int j0) {
    #pragma unroll
    for (int p = 0; p < 2; ++p) {
      int c = p * 256 + tid;
      int row = c >> 3, off = c & 7;
      kreg[p] = *reinterpret_cast<const uint4*>(kbase + (size_t)(j0 + row) * qstr + off * 8);
      vreg[p] = *reinterpret_cast<const uint4*>(vbase + (size_t)row * N_TOK + j0 + off * 8);
    }
  };
  auto commit = [&](int buf) {
    #pragma unroll
    for (int p = 0; p < 2; ++p) {
      int c = p * 256 + tid;
      int row = c >> 3, off = c & 7;
      int sw = row * 64 + ((off * 8) ^ ((row & 7) << 3));
      *reinterpret_cast<uint4*>(&Kl[buf][sw]) = kreg[p];
      *reinterpret_cast<uint4*>(&Vl[buf][sw]) = vreg[p];
    }
  };

  issue(0); commit(0);
  int cur = 0;
  for (int jt = 0; jt < N_TOK / 64; ++jt) {
    __syncthreads();
    if (jt + 1 < N_TOK / 64) issue((jt + 1) * 64);   // T14: hide HBM under compute

    // --- S^T = K · Q^T : 2 kv-subtiles x 4 k-steps of 32x32x16 ---
    f32x16 sacc0 = zero16(), sacc1 = zero16();
    #pragma unroll
    for (int f = 0; f < 4; ++f) {
      int r0 = q5;            // kv row, subtile 0
      int r1 = 32 + q5;       // kv row, subtile 1
      bf16x8 ka0 = *reinterpret_cast<const bf16x8*>(
          &Kl[cur][r0 * 64 + ((f * 16 + hi * 8) ^ ((r0 & 7) << 3))]);
      bf16x8 ka1 = *reinterpret_cast<const bf16x8*>(
          &Kl[cur][r1 * 64 + ((f * 16 + hi * 8) ^ ((r1 & 7) << 3))]);
      sacc0 = mfma32(ka0, qa[f], sacc0);
      sacc1 = mfma32(ka1, qa[f], sacc1);
    }

    // --- softmax over 64 kv: in-lane 32 + partner exchange ---
    float pe0[16], pe1[16];
    float tmax = -1e30f;
    #pragma unroll
    for (int r = 0; r < 16; ++r) {
      pe0[r] = sacc0[r] * SCALE_;
      pe1[r] = sacc1[r] * SCALE_;
      tmax = fmaxf(tmax, fmaxf(pe0[r], pe1[r]));
    }
    tmax = fmaxf(tmax, __shfl_xor(tmax, 32));
    float mn = fmaxf(m, tmax);
    float al = __expf(m - mn);
    m = mn;
    float ps = 0.f;
    #pragma unroll
    for (int r = 0; r < 16; ++r) {
      pe0[r] = __expf(pe0[r] - mn); ps += pe0[r];
      pe1[r] = __expf(pe1[r] - mn); ps += pe1[r];
    }
    ps += __shfl_xor(ps, 32);
    l = l * al + ps;
    oacc[0] *= al;
    oacc[1] *= al;

    // --- P^T -> bf16 B-frags (pack pairs, exchange halves) ---
    // lane holds P^T[kv][q]: kv5 pairs per packed word t:
    //   t=0:{0,1}+4hi  t=1:{2,3}+4hi  t=2:{8,9}+4hi  t=3:{10,11}+4hi
    //   t=4..7: +16
    unsigned int cc0[8], cc1[8], dd0[8], dd1[8];
    #pragma unroll
    for (int t = 0; t < 8; ++t) {
      union { __bf16 hh[2]; unsigned int u; } p0, p1;
      p0.hh[0] = (__bf16)pe0[2 * t]; p0.hh[1] = (__bf16)pe0[2 * t + 1];
      p1.hh[0] = (__bf16)pe1[2 * t]; p1.hh[1] = (__bf16)pe1[2 * t + 1];
      cc0[t] = p0.u; cc1[t] = p1.u;
      dd0[t] = __shfl_xor(p0.u, 32);
      dd1[t] = __shfl_xor(p1.u, 32);
    }
    // B-frag pb[ks]: col=q, k = kv = ks*16 + 8*hi + j   (ks = sub*2 + half)
    bf16x8 pb[4];
    #pragma unroll
    for (int half = 0; half < 2; ++half) {
      int t0 = half * 4;
      union { unsigned int w[4]; bf16x8 v; } u0, u1;
      u0.w[0] = hi ? dd0[t0 + 2] : cc0[t0 + 0];
      u0.w[1] = hi ? dd0[t0 + 3] : cc0[t0 + 1];
      u0.w[2] = hi ? cc0[t0 + 2] : dd0[t0 + 0];
      u0.w[3] = hi ? cc0[t0 + 3] : dd0[t0 + 1];
      u1.w[0] = hi ? dd1[t0 + 2] : cc1[t0 + 0];
      u1.w[1] = hi ? dd1[t0 + 3] : cc1[t0 + 1];
      u1.w[2] = hi ? cc1[t0 + 2] : dd1[t0 + 0];
      u1.w[3] = hi ? cc1[t0 + 3] : dd1[t0 + 1];
      pb[half] = u0.v;
      pb[2 + half] = u1.v;
    }

    // --- O^T += V^T · P^T : 2 d-tiles x 4 kv-steps ---
    #pragma unroll
    for (int dt = 0; dt < 2; ++dt) {
      int row = dt * 32 + q5;   // d row
      #pragma unroll
      for (int ks = 0; ks < 4; ++ks) {
        bf16x8 va = *reinterpret_cast<const bf16x8*>(
            &Vl[cur][row * 64 + ((ks * 16 + hi * 8) ^ ((row & 7) << 3))]);
        oacc[dt] = mfma32(va, pb[ks], oacc[dt]);
      }
    }
    if (jt + 1 < N_TOK / 64) commit(cur ^ 1);
    cur ^= 1;
  }

  // --- epilogue: O[q][d] = O^T[d][q] / l ; d = dt*32 + 8*rq + 4*hi + (0..3)
  float inv = 1.0f / l;
  unsigned short* ob = o + (size_t)(b * N_TOK + qrow) * DIM_ + h * DH_;
  #pragma unroll
  for (int dt = 0; dt < 2; ++dt)
    #pragma unroll
    for (int rq = 0; rq < 4; ++rq) {
      ushort4 st;
      st.x = f2bf(oacc[dt][rq * 4 + 0] * inv);
      st.y = f2bf(oacc[dt][rq * 4 + 1] * inv);
      st.z = f2bf(oacc[dt][rq * 4 + 2] * inv);
      st.w = f2bf(oacc[dt][rq * 4 + 3] * inv);
      *reinterpret_cast<ushort4*>(ob + dt * 32 + rq * 8 + hi * 4) = st;
    }
}

// ---------------------------------------------------------------------------
extern "C" void kernel_launch(void* const* d_in, const int* in_sizes, int n_in,
                              void* d_out, int out_size, void* d_ws, size_t ws_size,
                              hipStream_t stream) {
  (void)in_sizes; (void)n_in; (void)out_size; (void)ws_size;
  const float* x_in = (const float*)d_in[0];
  const float* Wqkv = (const float*)d_in[1];
  const float* bqkv = (const float*)d_in[2];
  const float* Wo   = (const float*)d_in[3];
  const float* bo   = (const float*)d_in[4];
  const float* W1   = (const float*)d_in[5];
  const float* bm1  = (const float*)d_in[6];
  const float* W2   = (const float*)d_in[7];
  const float* bm2  = (const float*)d_in[8];
  const float* ln1g = (const float*)d_in[9];
  const float* ln1b = (const float*)d_in[10];
  const float* ln2g = (const float*)d_in[11];
  const float* ln2b = (const float*)d_in[12];
  float* x = (float*)d_out;                  // residual stream, fp32, in-place

  char* ws = (char*)d_ws;
  unsigned short* wt  = (unsigned short*)(ws);                              // 8 MB
  unsigned short* hbf = (unsigned short*)(ws + (size_t)8  * 1024 * 1024);   // 8 MB
  unsigned short* qkv = (unsigned short*)(ws + (size_t)16 * 1024 * 1024);   // 24 MB
  unsigned short* vtb = (unsigned short*)(ws + (size_t)40 * 1024 * 1024);   // 8 MB
  unsigned short* ob  = (unsigned short*)(ws + (size_t)48 * 1024 * 1024);   // 8 MB
  unsigned short* mid = (unsigned short*)(ws + (size_t)56 * 1024 * 1024);   // 32 MB

  hipMemcpyAsync(x, x_in, (size_t)MROWS_ * DIM_ * sizeof(float),
                 hipMemcpyDeviceToDevice, stream);

  for (int l = 0; l < DEPTH_; ++l) {
    const float* wqkv_l = Wqkv + (size_t)l * DIM_ * 3 * DIM_;
    const float* wo_l   = Wo   + (size_t)l * DIM_ * DIM_;
    const float* w1_l   = W1   + (size_t)l * DIM_ * HID_;
    const float* w2_l   = W2   + (size_t)l * HID_ * DIM_;

    // --- PreNorm + Attention ---
    ln_kernel<<<MROWS_, 256, 0, stream>>>(x, hbf, ln1g + l * DIM_, ln1b + l * DIM_);
    transpose_w<<<dim3(3 * DIM_ / 32, DIM_ / 32), 256, 0, stream>>>(wqkv_l, wt, DIM_, 3 * DIM_);
    gemm_kernel<EP_BF16><<<dim3(MROWS_ / 128, 3 * DIM_ / 128), 256, 0, stream>>>(
        hbf, wt, bqkv + (size_t)l * 3 * DIM_, qkv, nullptr, MROWS_, 3 * DIM_, DIM_);
    vtrans<<<dim3(N_TOK / 64, B_ * HEADS_), 256, 0, stream>>>(qkv, vtb);
    attn_kernel<<<dim3(N_TOK / 128, B_ * HEADS_), 256, 0, stream>>>(qkv, vtb, ob);
    transpose_w<<<dim3(DIM_ / 32, DIM_ / 32), 256, 0, stream>>>(wo_l, wt, DIM_, DIM_);
    gemm_kernel<EP_F32_RESID><<<dim3(MROWS_ / 128, DIM_ / 128), 256, 0, stream>>>(
        ob, wt, bo + (size_t)l * DIM_, nullptr, x, MROWS_, DIM_, DIM_);

    // --- PreNorm + MLP ---
    ln_kernel<<<MROWS_, 256, 0, stream>>>(x, hbf, ln2g + l * DIM_, ln2b + l * DIM_);
    transpose_w<<<dim3(HID_ / 32, DIM_ / 32), 256, 0, stream>>>(w1_l, wt, DIM_, HID_);
    gemm_kernel<EP_BF16_GELU><<<dim3(MROWS_ / 128, HID_ / 128), 256, 0, stream>>>(
        hbf, wt, bm1 + (size_t)l * HID_, mid, nullptr, MROWS_, HID_, DIM_);
    transpose_w<<<dim3(DIM_ / 32, HID_ / 32), 256, 0, stream>>>(w2_l, wt, HID_, DIM_);
    gemm_kernel<EP_F32_RESID><<<dim3(MROWS_ / 128, DIM_ / 128), 256, 0, stream>>>(
        mid, wt, bm2 + (size_t)l * DIM_, nullptr, x, MROWS_, DIM_, HID_);
  }
}